// Round 16
// baseline (149.322 us; speedup 1.0000x reference)
//
#include <hip/hip_runtime.h>
#include <math.h>

#define S 4096
#define DM 256

using short8 = __attribute__((ext_vector_type(8))) short;
using short4v = __attribute__((ext_vector_type(4))) short;
using f32x4 = __attribute__((ext_vector_type(4))) float;
using f32x16 = __attribute__((ext_vector_type(16))) float;

// 1/sqrt(32) * log2(e): fold into q so scores feed v_exp_f32 (2^x) directly
static constexpr float QK_SCALE_LOG2E = 0.17677669529663687f * 1.4426950408889634f;

__device__ __forceinline__ short f2bf(float f) {
  union { float f; unsigned u; } v;
  v.f = f;
  unsigned r = (v.u + 0x7FFFu + ((v.u >> 16) & 1u)) >> 16;
  return (short)r;
}

__device__ __forceinline__ float bf2f(short s) {
  union { unsigned u; float f; } v;
  v.u = ((unsigned)(unsigned short)s) << 16;
  return v.f;
}

__device__ __forceinline__ unsigned cvt_pk_bf16(float lo, float hi) {
  unsigned r;
  asm("v_cvt_pk_bf16_f32 %0, %1, %2" : "=v"(r) : "v"(lo), "v"(hi));
  return r;
}

__device__ __forceinline__ float fexp2(float x) {
  float r;
  asm("v_exp_f32 %0, %1" : "=v"(r) : "v"(x));
  return r;
}

__device__ __forceinline__ int pad_idx(int s) {
  int d = s >> 8, h = (s >> 4) & 15, w = s & 15;
  return ((d + 1) * 18 + (h + 1)) * 18 + (w + 1);
}

// ---------- fused prep: xpad (coalesced plane transpose) | w1t/w2t (coalesced
// LDS transpose, padded) | qkv/ffn casts | hpad halo zero ----------
__global__ __launch_bounds__(256) void k_prep(const float* __restrict__ x,
                                              const float* __restrict__ c1w,
                                              const float* __restrict__ c2w,
                                              const float* __restrict__ qw,
                                              const float* __restrict__ kw,
                                              const float* __restrict__ vw,
                                              const float* __restrict__ fw,
                                              short* __restrict__ xpad,
                                              short* __restrict__ w1t,
                                              short* __restrict__ w2t,
                                              short* __restrict__ wqkvf,
                                              short* __restrict__ hpad) {
  __shared__ short tlds[16896];  // xpad: 256 x pitch66; w2t: <=7128
  int bid = blockIdx.x, tid = threadIdx.x;
  if (bid < 18) {                         // xpad: one block per pd plane
    int pd = bid;
    if (pd == 0 || pd == 17) {
      for (int i = tid; i < 20736; i += 256) xpad[pd * 20736 + i] = 0;
    } else {
      const float* xs = x + (pd - 1) * 256;
      for (int i = tid; i < 16384; i += 256) {
        int c = i >> 8, t = i & 255;
        tlds[t * 66 + c] = f2bf(xs[c * 4096 + t]);  // coalesced along t
      }
      __syncthreads();
      for (int i = tid; i < 20736; i += 256) {
        int r = i >> 6, c = i & 63;
        int ph = r / 18, pw = r - ph * 18;
        short v = 0;
        if ((unsigned)(ph - 1) < 16u && (unsigned)(pw - 1) < 16u)
          v = tlds[((ph - 1) * 16 + (pw - 1)) * 66 + c];
        xpad[(pd * 324 + r) * 64 + c] = v;          // coalesced along c
      }
    }
  } else if (bid < 274) {                 // w1t: one block per o; coalesced both sides
    int o = bid - 18;
    const float* src = c1w + o * 1728;
    for (int t = tid; t < 1728; t += 256) {
      int ic = t / 27, off = t - ic * 27;
      tlds[off * 72 + ic] = f2bf(src[t]);
    }
    __syncthreads();
    for (int u = tid; u < 1728; u += 256) {
      int off = u >> 6, ic = u & 63;
      w1t[o * 1728 + u] = tlds[off * 72 + ic];
    }
  } else if (bid < 338) {                 // w2t: one block per o
    int o = bid - 274;
    const float* src = c2w + o * 6912;
    for (int t = tid; t < 6912; t += 256) {
      int ic = t / 27, off = t - ic * 27;
      tlds[off * 264 + ic] = f2bf(src[t]);
    }
    __syncthreads();
    for (int u = tid; u < 6912; u += 256) {
      int off = u >> 8, ic = u & 255;
      w2t[o * 6912 + u] = tlds[off * 264 + ic];
    }
  } else if (bid < 1362) {                // q,k,v,ffn weight casts (4 x 65536)
    int idx = (bid - 338) * 256 + tid;
    int which = idx >> 16, r = idx & 65535;
    const float* src = (which == 0) ? qw : (which == 1) ? kw : (which == 2) ? vw : fw;
    wqkvf[idx] = f2bf(src[r]);
  } else {                                // hpad zero (full)
    int i = (bid - 1362) * 2048 + tid * 8;
    short8 z = {0, 0, 0, 0, 0, 0, 0, 0};
    *(short8*)(hpad + i) = z;
  }
}

// ---------- conv1 via MFMA, 32 m-rows/block (2 tiles share every weight frag) ----------
__global__ __launch_bounds__(256) void k_conv1m(const short* __restrict__ xpad,
                                                const short* __restrict__ wt,
                                                const float* __restrict__ bias,
                                                float* __restrict__ h0) {
  int bid = blockIdx.x;  // 256 = mt2(128) x ch(2)
  int mt2 = bid >> 1, ch = bid & 1;
  int tid = threadIdx.x, w = tid >> 6, lane = tid & 63, g = lane >> 4, c = lane & 15;
  int d = mt2 >> 3, h = (mt2 & 7) * 2;
  int nb = ch * 128 + w * 32;
  f32x4 accA0 = {}, accA1 = {}, accB0 = {}, accB1 = {};
  for (int off = 0; off < 27; ++off) {
    int kd = off / 9, r = off - kd * 9, kh = r / 3, kw = r - kh * 3;
    int rowb = ((d + kd) * 18 + h + kh) * 18 + kw + c;
#pragma unroll
    for (int kc = 0; kc < 2; ++kc) {
      short8 afA = *(const short8*)(xpad + rowb * 64 + kc * 32 + 8 * g);
      short8 afB = *(const short8*)(xpad + (rowb + 18) * 64 + kc * 32 + 8 * g);
      int kidx = off * 64 + kc * 32 + 8 * g;
      short8 b0 = *(const short8*)(wt + (nb + c) * 1728 + kidx);
      short8 b1 = *(const short8*)(wt + (nb + 16 + c) * 1728 + kidx);
      accA0 = __builtin_amdgcn_mfma_f32_16x16x32_bf16(afA, b0, accA0, 0, 0, 0);
      accA1 = __builtin_amdgcn_mfma_f32_16x16x32_bf16(afA, b1, accA1, 0, 0, 0);
      accB0 = __builtin_amdgcn_mfma_f32_16x16x32_bf16(afB, b0, accB0, 0, 0, 0);
      accB1 = __builtin_amdgcn_mfma_f32_16x16x32_bf16(afB, b1, accB1, 0, 0, 0);
    }
  }
  int o0 = nb + c, o1 = nb + 16 + c;
  float bv0 = bias[o0], bv1 = bias[o1];
  int sA = mt2 * 32 + 4 * g;
#pragma unroll
  for (int i = 0; i < 4; ++i) {
    h0[(sA + i) * 256 + o0] = accA0[i] + bv0;
    h0[(sA + i) * 256 + o1] = accA1[i] + bv1;
    h0[(sA + 16 + i) * 256 + o0] = accB0[i] + bv0;
    h0[(sA + 16 + i) * 256 + o1] = accB1[i] + bv1;
  }
}

// ---------- fused LN1 + QKV GEMM: 256 blocks x 3; LN recomputed per instance ----------
__global__ __launch_bounds__(256) void k_gemm_qkv(const float* __restrict__ h0,
                                                  const float* __restrict__ lng,
                                                  const float* __restrict__ lnb,
                                                  const short* __restrict__ wqb,
                                                  const short* __restrict__ wkb,
                                                  const short* __restrict__ wvb,
                                                  const float* __restrict__ qbi,
                                                  const float* __restrict__ kbi,
                                                  const float* __restrict__ vbi,
                                                  short* __restrict__ qb,
                                                  short* __restrict__ kb,
                                                  short* __restrict__ vt) {
  __shared__ short h2l[4096];  // 16 rows x 256 cols, XOR-swizzled
  int m0 = blockIdx.x * 16;
  int tid = threadIdx.x;
  // ---- phase 1: LN of h0 rows m0..m0+15 ----
  {
    int r = tid >> 4, cg = tid & 15;
    int row = m0 + r;
    float u[16];
    const float* hp = h0 + row * 256 + cg * 16;
#pragma unroll
    for (int i = 0; i < 16; i += 4) {
      float4 a = *(const float4*)(hp + i);
      u[i] = a.x; u[i + 1] = a.y; u[i + 2] = a.z; u[i + 3] = a.w;
    }
    float s1 = 0.f, s2 = 0.f;
#pragma unroll
    for (int i = 0; i < 16; ++i) { s1 += u[i]; s2 += u[i] * u[i]; }
    s1 += __shfl_xor(s1, 1); s2 += __shfl_xor(s2, 1);
    s1 += __shfl_xor(s1, 2); s2 += __shfl_xor(s2, 2);
    s1 += __shfl_xor(s1, 4); s2 += __shfl_xor(s2, 4);
    s1 += __shfl_xor(s1, 8); s2 += __shfl_xor(s2, 8);
    float m = s1 * (1.f / 256.f);
    float rstd = rsqrtf(s2 * (1.f / 256.f) - m * m + 1e-5f);
    float gv[16], bv[16];
#pragma unroll
    for (int i = 0; i < 16; i += 4) {
      float4 a = *(const float4*)(lng + cg * 16 + i);
      float4 b = *(const float4*)(lnb + cg * 16 + i);
      gv[i] = a.x; gv[i + 1] = a.y; gv[i + 2] = a.z; gv[i + 3] = a.w;
      bv[i] = b.x; bv[i + 1] = b.y; bv[i + 2] = b.z; bv[i + 3] = b.w;
    }
    union { unsigned uu[4]; short8 s8; } o0, o1;
#pragma unroll
    for (int i = 0; i < 8; i += 2) {
      float y0 = (u[i] - m) * rstd * gv[i] + bv[i];
      float y1 = (u[i + 1] - m) * rstd * gv[i + 1] + bv[i + 1];
      o0.uu[i >> 1] = cvt_pk_bf16(y0, y1);
      float y8 = (u[8 + i] - m) * rstd * gv[8 + i] + bv[8 + i];
      float y9 = (u[9 + i] - m) * rstd * gv[9 + i] + bv[9 + i];
      o1.uu[i >> 1] = cvt_pk_bf16(y8, y9);
    }
    char* base = (char*)h2l;
    *(short8*)(base + ((r * 512 + cg * 32) ^ ((r & 7) << 4))) = o0.s8;
    *(short8*)(base + ((r * 512 + cg * 32 + 16) ^ ((r & 7) << 4))) = o1.s8;
  }
  __syncthreads();
  // ---- phase 2: GEMM ----
  int y = blockIdx.y;
  const short* wb = (y == 0) ? wqb : ((y == 1) ? wkb : wvb);
  int w = tid >> 6, lane = tid & 63, g = lane >> 4, c = lane & 15;
  int nb = w * 64;
  f32x4 acc[4];
#pragma unroll
  for (int n = 0; n < 4; ++n) acc[n] = {0.f, 0.f, 0.f, 0.f};
  const char* abase = (const char*)h2l;
#pragma unroll 2
  for (int k0 = 0; k0 < 256; k0 += 32) {
    short8 af = *(const short8*)(abase + ((c * 512 + (k0 + 8 * g) * 2) ^ ((c & 7) << 4)));
#pragma unroll
    for (int n = 0; n < 4; ++n) {
      short8 bf = *(const short8*)(wb + (nb + 16 * n + c) * 256 + k0 + 8 * g);
      acc[n] = __builtin_amdgcn_mfma_f32_16x16x32_bf16(af, bf, acc[n], 0, 0, 0);
    }
  }
  if (y < 2) {
    const float* bi = (y == 0) ? qbi : kbi;
    float sc = (y == 0) ? QK_SCALE_LOG2E : 1.f;
    short* ob = (y == 0) ? qb : kb;
#pragma unroll
    for (int n = 0; n < 4; ++n) {
      int o = nb + 16 * n + c;
      float bvv = bi[o];
      int hh = o >> 5, dj = o & 31;
#pragma unroll
      for (int i = 0; i < 4; ++i) {
        int s = m0 + 4 * g + i;
        ob[((size_t)hh * S + s) * 32 + dj] = f2bf((acc[n][i] + bvv) * sc);
      }
    }
  } else {
#pragma unroll
    for (int n = 0; n < 4; ++n) {
      int o = nb + 16 * n + c;
      float bvv = vbi[o];
      short4v st;
#pragma unroll
      for (int i = 0; i < 4; ++i) st[i] = f2bf(acc[n][i] + bvv);
      *(short4v*)(vt + (size_t)o * S + m0 + 4 * g) = st;
    }
  }
}

// ---------- attn pass 1: 32x32 MFMA; partial lsum over a q-eighth.
// XCD swizzle: h = bid & 7 so each head's blocks share one XCD's L2. ----------
__global__ __launch_bounds__(256) void k_attn1(const short* __restrict__ qb,
                                               const short* __restrict__ kb,
                                               float* __restrict__ lpart) {
  int bid = blockIdx.x;  // 2048
  int h = bid & 7;
  int rest = bid >> 3;       // 256 = kt(32) x qs(8)
  int kt = rest >> 3, qs = rest & 7;
  int tid = threadIdx.x;
  int w = tid >> 6, lane = tid & 63;
  int lo = lane & 31, hi = lane >> 5;
  int k0 = kt * 128 + w * 32;
  const size_t hb = (size_t)h * S;
  const short* krow = kb + (hb + k0 + lo) * 32;
  short8 ak0 = *(const short8*)(krow + 8 * hi);
  short8 ak1 = *(const short8*)(krow + 16 + 8 * hi);
  f32x16 ls = {};
  const f32x16 z16 = {};
  int qend = qs * 512 + 512;
  for (int q0 = qs * 512; q0 < qend; q0 += 32) {
    short8 bq0 = *(const short8*)(qb + (hb + q0 + lo) * 32 + 8 * hi);
    short8 bq1 = *(const short8*)(qb + (hb + q0 + lo) * 32 + 16 + 8 * hi);
    __builtin_amdgcn_s_setprio(1);
    f32x16 p = __builtin_amdgcn_mfma_f32_32x32x16_bf16(ak0, bq0, z16, 0, 0, 0);
    p = __builtin_amdgcn_mfma_f32_32x32x16_bf16(ak1, bq1, p, 0, 0, 0);
    __builtin_amdgcn_s_setprio(0);
#pragma unroll
    for (int r = 0; r < 16; ++r) ls[r] += fexp2(p[r]);
  }
#pragma unroll
  for (int r = 0; r < 16; ++r) {
    float v = ls[r];
    v += __shfl_xor(v, 1);
    v += __shfl_xor(v, 2);
    v += __shfl_xor(v, 4);
    v += __shfl_xor(v, 8);
    v += __shfl_xor(v, 16);
    ls[r] = v;
  }
  if (lo == 0) {
#pragma unroll
    for (int r = 0; r < 16; ++r)
      lpart[qs * 32768 + h * 4096 + k0 + (r & 3) + 8 * (r >> 2) + 4 * hi] = ls[r];
  }
}

// vt[row][k] *= 1/l[h][k], with l computed inline from the 8 lpart slices.
// 512 blocks: 512*256 threads x 8 shorts = 1M = exactly vt's 256x4096.
__global__ __launch_bounds__(256) void k_scalevt(short* __restrict__ vt,
                                                 const float* __restrict__ lpart) {
  int idx = blockIdx.x * 256 + threadIdx.x;  // 131072
  int row = idx >> 9;
  int col0 = (idx & 511) << 3;
  int h = row >> 5;
  const float* lp = lpart + h * 4096 + col0;
  float4 s0 = {0.f, 0.f, 0.f, 0.f}, s1 = {0.f, 0.f, 0.f, 0.f};
#pragma unroll
  for (int j = 0; j < 8; ++j) {
    float4 a = *(const float4*)(lp + j * 32768);
    float4 b = *(const float4*)(lp + j * 32768 + 4);
    s0.x += a.x; s0.y += a.y; s0.z += a.z; s0.w += a.w;
    s1.x += b.x; s1.y += b.y; s1.z += b.z; s1.w += b.w;
  }
  float4 l0, l1;
  l0.x = 1.f / s0.x; l0.y = 1.f / s0.y; l0.z = 1.f / s0.z; l0.w = 1.f / s0.w;
  l1.x = 1.f / s1.x; l1.y = 1.f / s1.y; l1.z = 1.f / s1.z; l1.w = 1.f / s1.w;
  short8 v = *(short8*)(vt + (size_t)row * S + col0);
  union { unsigned u[4]; short8 s8; } r;
  r.u[0] = cvt_pk_bf16(bf2f(v[0]) * l0.x, bf2f(v[1]) * l0.y);
  r.u[1] = cvt_pk_bf16(bf2f(v[2]) * l0.z, bf2f(v[3]) * l0.w);
  r.u[2] = cvt_pk_bf16(bf2f(v[4]) * l1.x, bf2f(v[5]) * l1.y);
  r.u[3] = cvt_pk_bf16(bf2f(v[6]) * l1.z, bf2f(v[7]) * l1.w);
  *(short8*)(vt + (size_t)row * S + col0) = r.s8;
}

// ---------- attn pass 2: 32x32 MFMA, swapped QK, zero LDS, k-split x8,
// dual q-tiles + K&V-prefetch pipeline + XCD swizzle ----------
__global__ __launch_bounds__(256, 4) void k_attn2(const short* __restrict__ qb,
                                                  const short* __restrict__ kb,
                                                  const short* __restrict__ vt,
                                                  short* __restrict__ parts) {
  int bid = blockIdx.x;  // 1024
  int h = bid & 7;
  int rest = bid >> 3;       // 128 = qt(16) x ks(8)
  int qt = rest >> 3, ks = rest & 7;
  int tid = threadIdx.x;
  int w = tid >> 6, lane = tid & 63;
  int lo = lane & 31, hi = lane >> 5;
  // sigma: swap quartets [4-7]<->[8-11] and [20-23]<->[24-27]
  int sl = lo ^ ((((lo >> 2) ^ (lo >> 3)) & 1) * 12);
  int q0a = qt * 256 + w * 64;
  int q0b = q0a + 32;
  const size_t hb = (size_t)h * S;
  short8 bqa0 = *(const short8*)(qb + (hb + q0a + lo) * 32 + 8 * hi);
  short8 bqa1 = *(const short8*)(qb + (hb + q0a + lo) * 32 + 16 + 8 * hi);
  short8 bqb0 = *(const short8*)(qb + (hb + q0b + lo) * 32 + 8 * hi);
  short8 bqb1 = *(const short8*)(qb + (hb + q0b + lo) * 32 + 16 + 8 * hi);
  f32x16 accA = {}, accB = {};
  const short* krow = kb + (hb + sl) * 32;
  const short* vrow = vt + ((size_t)(h * 32) + lo) * S;
  const f32x16 z16 = {};
  int k0 = ks * 512;
  // prologue: load first K and V frags
  short8 ak0 = *(const short8*)(krow + (size_t)k0 * 32 + 8 * hi);
  short8 ak1 = *(const short8*)(krow + (size_t)k0 * 32 + 16 + 8 * hi);
  short8 bv0 = *(const short8*)(vrow + k0 + 8 * hi);
  short8 bv1 = *(const short8*)(vrow + k0 + 16 + 8 * hi);
#pragma unroll 1
  for (int it = 0; it < 16; ++it) {
    int kn = k0 + 32;
    // prefetch next K and V (last iter overruns 64B into adjacent live ws:
    // valid memory, values unused, deterministic)
    short8 nak0 = *(const short8*)(krow + (size_t)kn * 32 + 8 * hi);
    short8 nak1 = *(const short8*)(krow + (size_t)kn * 32 + 16 + 8 * hi);
    short8 nbv0 = *(const short8*)(vrow + kn + 8 * hi);
    short8 nbv1 = *(const short8*)(vrow + kn + 16 + 8 * hi);
    __builtin_amdgcn_s_setprio(1);
    f32x16 pA = __builtin_amdgcn_mfma_f32_32x32x16_bf16(ak0, bqa0, z16, 0, 0, 0);
    f32x16 pB = __builtin_amdgcn_mfma_f32_32x32x16_bf16(ak0, bqb0, z16, 0, 0, 0);
    pA = __builtin_amdgcn_mfma_f32_32x32x16_bf16(ak1, bqa1, pA, 0, 0, 0);
    pB = __builtin_amdgcn_mfma_f32_32x32x16_bf16(ak1, bqb1, pB, 0, 0, 0);
    __builtin_amdgcn_s_setprio(0);
    union { unsigned u[4]; short8 s8; } fA0, fA1, fB0, fB1;
#pragma unroll
    for (int m = 0; m < 4; ++m)
      fA0.u[m] = cvt_pk_bf16(fexp2(pA[2 * m]), fexp2(pA[2 * m + 1]));
#pragma unroll
    for (int m = 0; m < 4; ++m)
      fA1.u[m] = cvt_pk_bf16(fexp2(pA[8 + 2 * m]), fexp2(pA[9 + 2 * m]));
#pragma unroll
    for (int m = 0; m < 4; ++m)
      fB0.u[m] = cvt_pk_bf16(fexp2(pB[2 * m]), fexp2(pB[2 * m + 1]));
#pragma unroll
    for (int m = 0; m < 4; ++m)
      fB1.u[m] = cvt_pk_bf16(fexp2(pB[8 + 2 * m]), fexp2(pB[9 + 2 * m]));
    __builtin_amdgcn_s_setprio(1);
    accA = __builtin_amdgcn_mfma_f32_32x32x16_bf16(fA0.s8, bv0, accA, 0, 0, 0);
    accB = __builtin_amdgcn_mfma_f32_32x32x16_bf16(fB0.s8, bv0, accB, 0, 0, 0);
    accA = __builtin_amdgcn_mfma_f32_32x32x16_bf16(fA1.s8, bv1, accA, 0, 0, 0);
    accB = __builtin_amdgcn_mfma_f32_32x32x16_bf16(fB1.s8, bv1, accB, 0, 0, 0);
    __builtin_amdgcn_s_setprio(0);
    ak0 = nak0;
    ak1 = nak1;
    bv0 = nbv0;
    bv1 = nbv1;
    k0 = kn;
  }
  short* part = parts + (size_t)ks * (S * DM);
  int col = h * 32 + lo;
#pragma unroll
  for (int r = 0; r < 16; ++r) {
    int qrel = (r & 3) + 8 * (r >> 2) + 4 * hi;
    part[(q0a + qrel) * 256 + col] = f2bf(accA[r]);
    part[(q0b + qrel) * 256 + col] = f2bf(accB[r]);
  }
}

// ---------- fused combine + LN2 + FFN GEMM: 256 blocks, 16 rows each.
// Recomputes LN1 from h0 (identical fp32 math), adds 8 bf16 parts -> xt (LDS),
// LN2 -> swizzled bf16 LDS A-tile, then GEMM + relu + residual -> hpad. ----------
__global__ __launch_bounds__(256) void k_ffn_fused(const float* __restrict__ h0,
                                                   const short* __restrict__ parts,
                                                   const float* __restrict__ lng,
                                                   const float* __restrict__ lnb,
                                                   const short* __restrict__ wb,
                                                   const float* __restrict__ bi,
                                                   short* __restrict__ hpad) {
  __shared__ short h2l[4096];       // LN2 output bf16, XOR-swizzled
  __shared__ float xtl[16][256];    // xt fp32 (residual)
  int m0 = blockIdx.x * 16;
  int tid = threadIdx.x;
  {
    int r = tid >> 4, cg = tid & 15;
    int row = m0 + r;
    float u[16];
    const float* hp = h0 + row * 256 + cg * 16;
#pragma unroll
    for (int i = 0; i < 16; i += 4) {
      float4 a = *(const float4*)(hp + i);
      u[i] = a.x; u[i + 1] = a.y; u[i + 2] = a.z; u[i + 3] = a.w;
    }
    float s1 = 0.f, s2 = 0.f;
#pragma unroll
    for (int i = 0; i < 16; ++i) { s1 += u[i]; s2 += u[i] * u[i]; }
    s1 += __shfl_xor(s1, 1); s2 += __shfl_xor(s2, 1);
    s1 += __shfl_xor(s1, 2); s2 += __shfl_xor(s2, 2);
    s1 += __shfl_xor(s1, 4); s2 += __shfl_xor(s2, 4);
    s1 += __shfl_xor(s1, 8); s2 += __shfl_xor(s2, 8);
    float m1 = s1 * (1.f / 256.f);
    float rstd1 = rsqrtf(s2 * (1.f / 256.f) - m1 * m1 + 1e-5f);
    float gv[16], bvv[16];
#pragma unroll
    for (int i = 0; i < 16; i += 4) {
      float4 a = *(const float4*)(lng + cg * 16 + i);
      float4 b = *(const float4*)(lnb + cg * 16 + i);
      gv[i] = a.x; gv[i + 1] = a.y; gv[i + 2] = a.z; gv[i + 3] = a.w;
      bvv[i] = b.x; bvv[i + 1] = b.y; bvv[i + 2] = b.z; bvv[i + 3] = b.w;
    }
    float xv[16];
#pragma unroll
    for (int i = 0; i < 16; ++i) xv[i] = (u[i] - m1) * rstd1 * gv[i] + bvv[i];
    const int SD4 = S * DM;
#pragma unroll
    for (int j = 0; j < 8; ++j) {
      const short* pp = parts + j * SD4 + row * 256 + cg * 16;
      short8 p0 = *(const short8*)(pp);
      short8 p1 = *(const short8*)(pp + 8);
#pragma unroll
      for (int i = 0; i < 8; ++i) { xv[i] += bf2f(p0[i]); xv[8 + i] += bf2f(p1[i]); }
    }
    s1 = 0.f; s2 = 0.f;
#pragma unroll
    for (int i = 0; i < 16; ++i) { s1 += xv[i]; s2 += xv[i] * xv[i]; }
    s1 += __shfl_xor(s1, 1); s2 += __shfl_xor(s2, 1);
    s1 += __shfl_xor(s1, 2); s2 += __shfl_xor(s2, 2);
    s1 += __shfl_xor(s1, 4); s2 += __shfl_xor(s2, 4);
    s1 += __shfl_xor(s1, 8); s2 += __shfl_xor(s2, 8);
    float m2 = s1 * (1.f / 256.f);
    float rstd2 = rsqrtf(s2 * (1.f / 256.f) - m2 * m2 + 1e-5f);
#pragma unroll
    for (int i = 0; i < 16; i += 4) {
      float4 a;
      a.x = xv[i]; a.y = xv[i + 1]; a.z = xv[i + 2]; a.w = xv[i + 3];
      *(float4*)(&xtl[r][cg * 16 + i]) = a;
    }
    union { unsigned uu[4]; short8 s8; } o0, o1;
#pragma unroll
    for (int i = 0; i < 8; i += 2) {
      float y0 = (xv[i] - m2) * rstd2 * gv[i] + bvv[i];
      float y1 = (xv[i + 1] - m2) * rstd2 * gv[i + 1] + bvv[i + 1];
      o0.uu[i >> 1] = cvt_pk_bf16(y0, y1);
      float y8 = (xv[8 + i] - m2) * rstd2 * gv[8 + i] + bvv[8 + i];
      float y9 = (xv[9 + i] - m2) * rstd2 * gv[9 + i] + bvv[9 + i];
      o1.uu[i >> 1] = cvt_pk_bf16(y8, y9);
    }
    char* base = (char*)h2l;
    *(short8*)(base + ((r * 512 + cg * 32) ^ ((r & 7) << 4))) = o0.s8;
    *(short8*)(base + ((r * 512 + cg * 32 + 16) ^ ((r & 7) << 4))) = o1.s8;
  }
  __syncthreads();
  // GEMM
  int w = tid >> 6, lane = tid & 63, g = lane >> 4, c = lane & 15;
  int nb = w * 64;
  f32x4 acc[4];
#pragma unroll
  for (int n = 0; n < 4; ++n) acc[n] = {0.f, 0.f, 0.f, 0.f};
  const char* abase = (const char*)h2l;
#pragma unroll 2
  for (int k0 = 0; k0 < 256; k0 += 32) {
    short8 af = *(const short8*)(abase + ((c * 512 + (k0 + 8 * g) * 2) ^ ((c & 7) << 4)));
#pragma unroll
    for (int n = 0; n < 4; ++n) {
      short8 bf = *(const short8*)(wb + (nb + 16 * n + c) * 256 + k0 + 8 * g);
      acc[n] = __builtin_amdgcn_mfma_f32_16x16x32_bf16(af, bf, acc[n], 0, 0, 0);
    }
  }
  int pr[4];
#pragma unroll
  for (int i = 0; i < 4; ++i) pr[i] = pad_idx(m0 + 4 * g + i) * 256;
#pragma unroll
  for (int n = 0; n < 4; ++n) {
    int o = nb + 16 * n + c;
    float bvv = bi[o];
#pragma unroll
    for (int i = 0; i < 4; ++i) {
      float v = acc[n][i] + bvv;
      v = v > 0.f ? v : 0.f;
      hpad[pr[i] + o] = f2bf(v + xtl[4 * g + i][o]);
    }
  }
}

// ---------- conv2 via MFMA, K-split x4, 32 m-rows/block (B-frag reuse x2) ----------
__global__ __launch_bounds__(256) void k_conv2m(const short* __restrict__ hpad,
                                                const short* __restrict__ wt,
                                                float* __restrict__ pbase) {
  __shared__ float red[3][32][65];
  int bid = blockIdx.x;  // 512 = mt2(128) x kh(4)
  int mt2 = bid >> 2, kh = bid & 3;
  int tid = threadIdx.x, w = tid >> 6, lane = tid & 63, g = lane >> 4, c = lane & 15;
  int d = mt2 >> 3, h = (mt2 & 7) * 2;
  f32x4 accA[4], accB[4];
#pragma unroll
  for (int n = 0; n < 4; ++n) { accA[n] = {0.f, 0.f, 0.f, 0.f}; accB[n] = {0.f, 0.f, 0.f, 0.f}; }
  int off0 = kh * 7;
  int offn = (kh == 3) ? 6 : 7;
  for (int off = off0 + w; off < off0 + offn; off += 4) {
    int kd = off / 9, rr = off - kd * 9, kkh = rr / 3, kw = rr - kkh * 3;
    int rowb = ((d + kd) * 18 + h + kkh) * 18 + kw + c;
    const short* arowA = hpad + rowb * 256;
    const short* arowB = hpad + (rowb + 18) * 256;
    const short* wrow = wt + off * 256;
#pragma unroll 2
    for (int kc = 0; kc < 8; ++kc) {
      short8 afA = *(const short8*)(arowA + kc * 32 + 8 * g);
      short8 afB = *(const short8*)(arowB + kc * 32 + 8 * g);
#pragma unroll
      for (int n = 0; n < 4; ++n) {
        short8 bf = *(const short8*)(wrow + (16 * n + c) * 6912 + kc * 32 + 8 * g);
        accA[n] = __builtin_amdgcn_mfma_f32_16x16x32_bf16(afA, bf, accA[n], 0, 0, 0);
        accB[n] = __builtin_amdgcn_mfma_f32_16x16x32_bf16(afB, bf, accB[n], 0, 0, 0);
      }
    }
  }
  if (w > 0) {
#pragma unroll
    for (int n = 0; n < 4; ++n)
#pragma unroll
      for (int i = 0; i < 4; ++i) {
        red[w - 1][n * 4 + i][lane] = accA[n][i];
        red[w - 1][16 + n * 4 + i][lane] = accB[n][i];
      }
  }
  __syncthreads();
  if (w == 0) {
    float* pbuf = pbase + (size_t)kh * (S * DM / 4);  // 64*4096 each
#pragma unroll
    for (int n = 0; n < 4; ++n) {
      int o = 16 * n + c;
      float4 stA, stB;
#pragma unroll
      for (int i = 0; i < 4; ++i) {
        float a = accA[n][i] + red[0][n * 4 + i][lane] + red[1][n * 4 + i][lane] + red[2][n * 4 + i][lane];
        float bb = accB[n][i] + red[0][16 + n * 4 + i][lane] + red[1][16 + n * 4 + i][lane] + red[2][16 + n * 4 + i][lane];
        ((float*)&stA)[i] = a;
        ((float*)&stB)[i] = bb;
      }
      *(float4*)(pbuf + o * 4096 + mt2 * 32 + 4 * g) = stA;
      *(float4*)(pbuf + o * 4096 + mt2 * 32 + 16 + 4 * g) = stB;
    }
  }
}

__global__ __launch_bounds__(256) void k_conv2fin(const float* __restrict__ pbase,
                                                  const float* __restrict__ bias,
                                                  float* __restrict__ out) {
  int idx4 = (blockIdx.x * 256 + threadIdx.x) * 4;  // 262144 total
  int o = idx4 >> 12;
  const int PS = S * DM / 4;  // 262144
  float4 a = *(const float4*)(pbase + idx4);
  float4 b = *(const float4*)(pbase + PS + idx4);
  float4 c = *(const float4*)(pbase + 2 * PS + idx4);
  float4 d = *(const float4*)(pbase + 3 * PS + idx4);
  float bv = bias[o];
  float4 r;
  r.x = a.x + b.x + c.x + d.x + bv;
  r.y = a.y + b.y + c.y + d.y + bv;
  r.z = a.z + b.z + c.z + d.z + bv;
  r.w = a.w + b.w + c.w + d.w + bv;
  *(float4*)(out + idx4) = r;
}

extern "C" void kernel_launch(void* const* d_in, const int* in_sizes, int n_in,
                              void* d_out, int out_size, void* d_ws, size_t ws_size,
                              hipStream_t stream) {
  const float* x   = (const float*)d_in[0];
  const float* c1w = (const float*)d_in[1];
  const float* c1b = (const float*)d_in[2];
  const float* lng = (const float*)d_in[3];
  const float* lnb = (const float*)d_in[4];
  const float* qw  = (const float*)d_in[5];
  const float* qbi = (const float*)d_in[6];
  const float* kw  = (const float*)d_in[7];
  const float* kbi = (const float*)d_in[8];
  const float* vw  = (const float*)d_in[9];
  const float* vbi = (const float*)d_in[10];
  const float* fw  = (const float*)d_in[11];
  const float* fbi = (const float*)d_in[12];
  const float* c2w = (const float*)d_in[13];
  const float* c2b = (const float*)d_in[14];
  float* out = (float*)d_out;
  float* ws = (float*)d_ws;

  const size_t SD = (size_t)S * DM;  // 1048576
  float* h0     = ws;                  // SD floats (live until ffn)
  short* partsb = (short*)(h0 + SD);   // 8*SD shorts (16MB)
  float* c2p    = (float*)partsb;      // alias: conv2 partials (parts dead by then)
  float* lpart  = (float*)(partsb + 8 * SD);  // 262144 floats
  short* qb     = (short*)(lpart + 262144);
  short* kb     = qb + SD;
  short* vt     = kb + SD;
  short* xpad   = vt + SD;             // 373248
  short* hpad   = xpad + 373248;       // 1492992
  short* w1t    = hpad + 1492992;      // 442368
  short* w2t    = w1t + 442368;        // 442368
  short* wqb    = w2t + 442368;        // 4 x 65536 contiguous
  short* wkb    = wqb + 65536;
  short* wvb    = wkb + 65536;
  short* wfb    = wvb + 65536;

  k_prep<<<2091, 256, 0, stream>>>(x, c1w, c2w, qw, kw, vw, fw,
                                   xpad, w1t, w2t, wqb, hpad);

  k_conv1m<<<256, 256, 0, stream>>>(xpad, w1t, c1b, h0);

  k_gemm_qkv<<<dim3(256, 3), 256, 0, stream>>>(h0, lng, lnb, wqb, wkb, wvb,
                                               qbi, kbi, vbi, qb, kb, vt);

  k_attn1<<<2048, 256, 0, stream>>>(qb, kb, lpart);
  k_scalevt<<<512, 256, 0, stream>>>(vt, lpart);
  k_attn2<<<1024, 256, 0, stream>>>(qb, kb, vt, partsb);

  k_ffn_fused<<<256, 256, 0, stream>>>(h0, partsb, lng, lnb, wfb, fbi, hpad);

  k_conv2m<<<512, 256, 0, stream>>>(hpad, w2t, c2p);
  k_conv2fin<<<256, 256, 0, stream>>>(c2p, c2b, out);
}

// Round 17
// 140.931 us; speedup vs baseline: 1.0595x; 1.0595x over previous
//
#include <hip/hip_runtime.h>
#include <math.h>

#define S 4096
#define DM 256

using short8 = __attribute__((ext_vector_type(8))) short;
using short4v = __attribute__((ext_vector_type(4))) short;
using f32x4 = __attribute__((ext_vector_type(4))) float;
using f32x16 = __attribute__((ext_vector_type(16))) float;

// 1/sqrt(32) * log2(e): fold into q so scores feed v_exp_f32 (2^x) directly
static constexpr float QK_SCALE_LOG2E = 0.17677669529663687f * 1.4426950408889634f;

__device__ __forceinline__ short f2bf(float f) {
  union { float f; unsigned u; } v;
  v.f = f;
  unsigned r = (v.u + 0x7FFFu + ((v.u >> 16) & 1u)) >> 16;
  return (short)r;
}

__device__ __forceinline__ float bf2f(short s) {
  union { unsigned u; float f; } v;
  v.u = ((unsigned)(unsigned short)s) << 16;
  return v.f;
}

__device__ __forceinline__ unsigned cvt_pk_bf16(float lo, float hi) {
  unsigned r;
  asm("v_cvt_pk_bf16_f32 %0, %1, %2" : "=v"(r) : "v"(lo), "v"(hi));
  return r;
}

__device__ __forceinline__ float fexp2(float x) {
  float r;
  asm("v_exp_f32 %0, %1" : "=v"(r) : "v"(x));
  return r;
}

__device__ __forceinline__ int pad_idx(int s) {
  int d = s >> 8, h = (s >> 4) & 15, w = s & 15;
  return ((d + 1) * 18 + (h + 1)) * 18 + (w + 1);
}

// ---------- fused prep: xpad | w1t/w2t (coalesced LDS transpose, padded) |
// qkv/ffn casts | hpad halo zero ----------
__global__ __launch_bounds__(256) void k_prep(const float* __restrict__ x,
                                              const float* __restrict__ c1w,
                                              const float* __restrict__ c2w,
                                              const float* __restrict__ qw,
                                              const float* __restrict__ kw,
                                              const float* __restrict__ vw,
                                              const float* __restrict__ fw,
                                              short* __restrict__ xpad,
                                              short* __restrict__ w1t,
                                              short* __restrict__ w2t,
                                              short* __restrict__ wqkvf,
                                              short* __restrict__ hpad) {
  __shared__ short tlds[7128];
  int bid = blockIdx.x, tid = threadIdx.x;
  if (bid < 1458) {                       // xpad: 5832*64
    int idx = bid * 256 + tid;
    int row = idx >> 6, c = idx & 63;
    int pd = row / 324, rem = row - pd * 324;
    int ph = rem / 18, pw = rem - ph * 18;
    short v = 0;
    if ((unsigned)(pd - 1) < 16u && (unsigned)(ph - 1) < 16u && (unsigned)(pw - 1) < 16u) {
      int s = (pd - 1) * 256 + (ph - 1) * 16 + (pw - 1);
      v = f2bf(x[c * 4096 + s]);
    }
    xpad[idx] = v;
  } else if (bid < 1714) {                // w1t: one block per o; coalesced both sides
    int o = bid - 1458;
    const float* src = c1w + o * 1728;
    for (int t = tid; t < 1728; t += 256) {
      int ic = t / 27, off = t - ic * 27;
      tlds[off * 72 + ic] = f2bf(src[t]);
    }
    __syncthreads();
    for (int u = tid; u < 1728; u += 256) {
      int off = u >> 6, ic = u & 63;
      w1t[o * 1728 + u] = tlds[off * 72 + ic];
    }
  } else if (bid < 1778) {                // w2t: one block per o
    int o = bid - 1714;
    const float* src = c2w + o * 6912;
    for (int t = tid; t < 6912; t += 256) {
      int ic = t / 27, off = t - ic * 27;
      tlds[off * 264 + ic] = f2bf(src[t]);
    }
    __syncthreads();
    for (int u = tid; u < 6912; u += 256) {
      int off = u >> 8, ic = u & 255;
      w2t[o * 6912 + u] = tlds[off * 264 + ic];
    }
  } else if (bid < 2802) {                // q,k,v,ffn weight casts (4 x 65536)
    int idx = (bid - 1778) * 256 + tid;
    int which = idx >> 16, r = idx & 65535;
    const float* src = (which == 0) ? qw : (which == 1) ? kw : (which == 2) ? vw : fw;
    wqkvf[idx] = f2bf(src[r]);
  } else {                                // hpad zero (full)
    int i = (bid - 2802) * 2048 + tid * 8;
    short8 z = {0, 0, 0, 0, 0, 0, 0, 0};
    *(short8*)(hpad + i) = z;
  }
}

// ---------- conv1 via MFMA, 32 m-rows/block (2 tiles share every weight frag) ----------
__global__ __launch_bounds__(256) void k_conv1m(const short* __restrict__ xpad,
                                                const short* __restrict__ wt,
                                                const float* __restrict__ bias,
                                                float* __restrict__ h0) {
  int bid = blockIdx.x;  // 256 = mt2(128) x ch(2)
  int mt2 = bid >> 1, ch = bid & 1;
  int tid = threadIdx.x, w = tid >> 6, lane = tid & 63, g = lane >> 4, c = lane & 15;
  int d = mt2 >> 3, h = (mt2 & 7) * 2;
  int nb = ch * 128 + w * 32;
  f32x4 accA0 = {}, accA1 = {}, accB0 = {}, accB1 = {};
  for (int off = 0; off < 27; ++off) {
    int kd = off / 9, r = off - kd * 9, kh = r / 3, kw = r - kh * 3;
    int rowb = ((d + kd) * 18 + h + kh) * 18 + kw + c;
#pragma unroll
    for (int kc = 0; kc < 2; ++kc) {
      short8 afA = *(const short8*)(xpad + rowb * 64 + kc * 32 + 8 * g);
      short8 afB = *(const short8*)(xpad + (rowb + 18) * 64 + kc * 32 + 8 * g);
      int kidx = off * 64 + kc * 32 + 8 * g;
      short8 b0 = *(const short8*)(wt + (nb + c) * 1728 + kidx);
      short8 b1 = *(const short8*)(wt + (nb + 16 + c) * 1728 + kidx);
      accA0 = __builtin_amdgcn_mfma_f32_16x16x32_bf16(afA, b0, accA0, 0, 0, 0);
      accA1 = __builtin_amdgcn_mfma_f32_16x16x32_bf16(afA, b1, accA1, 0, 0, 0);
      accB0 = __builtin_amdgcn_mfma_f32_16x16x32_bf16(afB, b0, accB0, 0, 0, 0);
      accB1 = __builtin_amdgcn_mfma_f32_16x16x32_bf16(afB, b1, accB1, 0, 0, 0);
    }
  }
  int o0 = nb + c, o1 = nb + 16 + c;
  float bv0 = bias[o0], bv1 = bias[o1];
  int sA = mt2 * 32 + 4 * g;
#pragma unroll
  for (int i = 0; i < 4; ++i) {
    h0[(sA + i) * 256 + o0] = accA0[i] + bv0;
    h0[(sA + i) * 256 + o1] = accA1[i] + bv1;
    h0[(sA + 16 + i) * 256 + o0] = accB0[i] + bv0;
    h0[(sA + 16 + i) * 256 + o1] = accB1[i] + bv1;
  }
}

// ---------- fused LN1 + QKV GEMM: 256 blocks x 3; LN recomputed per instance ----------
__global__ __launch_bounds__(256) void k_gemm_qkv(const float* __restrict__ h0,
                                                  const float* __restrict__ lng,
                                                  const float* __restrict__ lnb,
                                                  const short* __restrict__ wqb,
                                                  const short* __restrict__ wkb,
                                                  const short* __restrict__ wvb,
                                                  const float* __restrict__ qbi,
                                                  const float* __restrict__ kbi,
                                                  const float* __restrict__ vbi,
                                                  short* __restrict__ qb,
                                                  short* __restrict__ kb,
                                                  short* __restrict__ vt) {
  __shared__ short h2l[4096];  // 16 rows x 256 cols, XOR-swizzled
  int m0 = blockIdx.x * 16;
  int tid = threadIdx.x;
  // ---- phase 1: LN of h0 rows m0..m0+15 ----
  {
    int r = tid >> 4, cg = tid & 15;
    int row = m0 + r;
    float u[16];
    const float* hp = h0 + row * 256 + cg * 16;
#pragma unroll
    for (int i = 0; i < 16; i += 4) {
      float4 a = *(const float4*)(hp + i);
      u[i] = a.x; u[i + 1] = a.y; u[i + 2] = a.z; u[i + 3] = a.w;
    }
    float s1 = 0.f, s2 = 0.f;
#pragma unroll
    for (int i = 0; i < 16; ++i) { s1 += u[i]; s2 += u[i] * u[i]; }
    s1 += __shfl_xor(s1, 1); s2 += __shfl_xor(s2, 1);
    s1 += __shfl_xor(s1, 2); s2 += __shfl_xor(s2, 2);
    s1 += __shfl_xor(s1, 4); s2 += __shfl_xor(s2, 4);
    s1 += __shfl_xor(s1, 8); s2 += __shfl_xor(s2, 8);
    float m = s1 * (1.f / 256.f);
    float rstd = rsqrtf(s2 * (1.f / 256.f) - m * m + 1e-5f);
    float gv[16], bv[16];
#pragma unroll
    for (int i = 0; i < 16; i += 4) {
      float4 a = *(const float4*)(lng + cg * 16 + i);
      float4 b = *(const float4*)(lnb + cg * 16 + i);
      gv[i] = a.x; gv[i + 1] = a.y; gv[i + 2] = a.z; gv[i + 3] = a.w;
      bv[i] = b.x; bv[i + 1] = b.y; bv[i + 2] = b.z; bv[i + 3] = b.w;
    }
    union { unsigned uu[4]; short8 s8; } o0, o1;
#pragma unroll
    for (int i = 0; i < 8; i += 2) {
      float y0 = (u[i] - m) * rstd * gv[i] + bv[i];
      float y1 = (u[i + 1] - m) * rstd * gv[i + 1] + bv[i + 1];
      o0.uu[i >> 1] = cvt_pk_bf16(y0, y1);
      float y8 = (u[8 + i] - m) * rstd * gv[8 + i] + bv[8 + i];
      float y9 = (u[9 + i] - m) * rstd * gv[9 + i] + bv[9 + i];
      o1.uu[i >> 1] = cvt_pk_bf16(y8, y9);
    }
    char* base = (char*)h2l;
    *(short8*)(base + ((r * 512 + cg * 32) ^ ((r & 7) << 4))) = o0.s8;
    *(short8*)(base + ((r * 512 + cg * 32 + 16) ^ ((r & 7) << 4))) = o1.s8;
  }
  __syncthreads();
  // ---- phase 2: GEMM ----
  int y = blockIdx.y;
  const short* wb = (y == 0) ? wqb : ((y == 1) ? wkb : wvb);
  int w = tid >> 6, lane = tid & 63, g = lane >> 4, c = lane & 15;
  int nb = w * 64;
  f32x4 acc[4];
#pragma unroll
  for (int n = 0; n < 4; ++n) acc[n] = {0.f, 0.f, 0.f, 0.f};
  const char* abase = (const char*)h2l;
#pragma unroll 2
  for (int k0 = 0; k0 < 256; k0 += 32) {
    short8 af = *(const short8*)(abase + ((c * 512 + (k0 + 8 * g) * 2) ^ ((c & 7) << 4)));
#pragma unroll
    for (int n = 0; n < 4; ++n) {
      short8 bf = *(const short8*)(wb + (nb + 16 * n + c) * 256 + k0 + 8 * g);
      acc[n] = __builtin_amdgcn_mfma_f32_16x16x32_bf16(af, bf, acc[n], 0, 0, 0);
    }
  }
  if (y < 2) {
    const float* bi = (y == 0) ? qbi : kbi;
    float sc = (y == 0) ? QK_SCALE_LOG2E : 1.f;
    short* ob = (y == 0) ? qb : kb;
#pragma unroll
    for (int n = 0; n < 4; ++n) {
      int o = nb + 16 * n + c;
      float bvv = bi[o];
      int hh = o >> 5, dj = o & 31;
#pragma unroll
      for (int i = 0; i < 4; ++i) {
        int s = m0 + 4 * g + i;
        ob[((size_t)hh * S + s) * 32 + dj] = f2bf((acc[n][i] + bvv) * sc);
      }
    }
  } else {
#pragma unroll
    for (int n = 0; n < 4; ++n) {
      int o = nb + 16 * n + c;
      float bvv = vbi[o];
      short4v st;
#pragma unroll
      for (int i = 0; i < 4; ++i) st[i] = f2bf(acc[n][i] + bvv);
      *(short4v*)(vt + (size_t)o * S + m0 + 4 * g) = st;
    }
  }
}

// ---------- attn pass 1: 32x32 MFMA; partial lsum over a q-eighth.
// XCD swizzle: h = bid & 7 so each head's blocks share one XCD's L2. ----------
__global__ __launch_bounds__(256) void k_attn1(const short* __restrict__ qb,
                                               const short* __restrict__ kb,
                                               float* __restrict__ lpart) {
  int bid = blockIdx.x;  // 2048
  int h = bid & 7;
  int rest = bid >> 3;       // 256 = kt(32) x qs(8)
  int kt = rest >> 3, qs = rest & 7;
  int tid = threadIdx.x;
  int w = tid >> 6, lane = tid & 63;
  int lo = lane & 31, hi = lane >> 5;
  int k0 = kt * 128 + w * 32;
  const size_t hb = (size_t)h * S;
  const short* krow = kb + (hb + k0 + lo) * 32;
  short8 ak0 = *(const short8*)(krow + 8 * hi);
  short8 ak1 = *(const short8*)(krow + 16 + 8 * hi);
  f32x16 ls = {};
  const f32x16 z16 = {};
  int qend = qs * 512 + 512;
  for (int q0 = qs * 512; q0 < qend; q0 += 32) {
    short8 bq0 = *(const short8*)(qb + (hb + q0 + lo) * 32 + 8 * hi);
    short8 bq1 = *(const short8*)(qb + (hb + q0 + lo) * 32 + 16 + 8 * hi);
    __builtin_amdgcn_s_setprio(1);
    f32x16 p = __builtin_amdgcn_mfma_f32_32x32x16_bf16(ak0, bq0, z16, 0, 0, 0);
    p = __builtin_amdgcn_mfma_f32_32x32x16_bf16(ak1, bq1, p, 0, 0, 0);
    __builtin_amdgcn_s_setprio(0);
#pragma unroll
    for (int r = 0; r < 16; ++r) ls[r] += fexp2(p[r]);
  }
#pragma unroll
  for (int r = 0; r < 16; ++r) {
    float v = ls[r];
    v += __shfl_xor(v, 1);
    v += __shfl_xor(v, 2);
    v += __shfl_xor(v, 4);
    v += __shfl_xor(v, 8);
    v += __shfl_xor(v, 16);
    ls[r] = v;
  }
  if (lo == 0) {
#pragma unroll
    for (int r = 0; r < 16; ++r)
      lpart[qs * 32768 + h * 4096 + k0 + (r & 3) + 8 * (r >> 2) + 4 * hi] = ls[r];
  }
}

// vt[row][k] *= 1/l[h][k], with l computed inline from the 8 lpart slices.
// 512 blocks: 512*256 threads x 8 shorts = 1M = exactly vt's 256x4096.
__global__ __launch_bounds__(256) void k_scalevt(short* __restrict__ vt,
                                                 const float* __restrict__ lpart) {
  int idx = blockIdx.x * 256 + threadIdx.x;  // 131072
  int row = idx >> 9;
  int col0 = (idx & 511) << 3;
  int h = row >> 5;
  const float* lp = lpart + h * 4096 + col0;
  float4 s0 = {0.f, 0.f, 0.f, 0.f}, s1 = {0.f, 0.f, 0.f, 0.f};
#pragma unroll
  for (int j = 0; j < 8; ++j) {
    float4 a = *(const float4*)(lp + j * 32768);
    float4 b = *(const float4*)(lp + j * 32768 + 4);
    s0.x += a.x; s0.y += a.y; s0.z += a.z; s0.w += a.w;
    s1.x += b.x; s1.y += b.y; s1.z += b.z; s1.w += b.w;
  }
  float4 l0, l1;
  l0.x = 1.f / s0.x; l0.y = 1.f / s0.y; l0.z = 1.f / s0.z; l0.w = 1.f / s0.w;
  l1.x = 1.f / s1.x; l1.y = 1.f / s1.y; l1.z = 1.f / s1.z; l1.w = 1.f / s1.w;
  short8 v = *(short8*)(vt + (size_t)row * S + col0);
  union { unsigned u[4]; short8 s8; } r;
  r.u[0] = cvt_pk_bf16(bf2f(v[0]) * l0.x, bf2f(v[1]) * l0.y);
  r.u[1] = cvt_pk_bf16(bf2f(v[2]) * l0.z, bf2f(v[3]) * l0.w);
  r.u[2] = cvt_pk_bf16(bf2f(v[4]) * l1.x, bf2f(v[5]) * l1.y);
  r.u[3] = cvt_pk_bf16(bf2f(v[6]) * l1.z, bf2f(v[7]) * l1.w);
  *(short8*)(vt + (size_t)row * S + col0) = r.s8;
}

// ---------- attn pass 2: 32x32 MFMA, swapped QK, zero LDS, k-split x8,
// dual q-tiles + K-prefetch + XCD swizzle (head-per-XCD L2 locality) ----------
__global__ __launch_bounds__(256, 4) void k_attn2(const short* __restrict__ qb,
                                                  const short* __restrict__ kb,
                                                  const short* __restrict__ vt,
                                                  short* __restrict__ parts) {
  int bid = blockIdx.x;  // 1024
  int h = bid & 7;
  int rest = bid >> 3;       // 128 = qt(16) x ks(8)
  int qt = rest >> 3, ks = rest & 7;
  int tid = threadIdx.x;
  int w = tid >> 6, lane = tid & 63;
  int lo = lane & 31, hi = lane >> 5;
  // sigma: swap quartets [4-7]<->[8-11] and [20-23]<->[24-27]
  int sl = lo ^ ((((lo >> 2) ^ (lo >> 3)) & 1) * 12);
  int q0a = qt * 256 + w * 64;
  int q0b = q0a + 32;
  const size_t hb = (size_t)h * S;
  short8 bqa0 = *(const short8*)(qb + (hb + q0a + lo) * 32 + 8 * hi);
  short8 bqa1 = *(const short8*)(qb + (hb + q0a + lo) * 32 + 16 + 8 * hi);
  short8 bqb0 = *(const short8*)(qb + (hb + q0b + lo) * 32 + 8 * hi);
  short8 bqb1 = *(const short8*)(qb + (hb + q0b + lo) * 32 + 16 + 8 * hi);
  f32x16 accA = {}, accB = {};
  const short* krow = kb + (hb + sl) * 32;
  const short* vrow = vt + ((size_t)(h * 32) + lo) * S;
  const f32x16 z16 = {};
  int k0 = ks * 512;
  short8 ak0 = *(const short8*)(krow + (size_t)k0 * 32 + 8 * hi);
  short8 ak1 = *(const short8*)(krow + (size_t)k0 * 32 + 16 + 8 * hi);
#pragma unroll 1
  for (int it = 0; it < 16; ++it) {
    int kn = k0 + 32;
    // prefetch next K (last iter overruns 64B into adjacent ws: valid, unused)
    short8 nak0 = *(const short8*)(krow + (size_t)kn * 32 + 8 * hi);
    short8 nak1 = *(const short8*)(krow + (size_t)kn * 32 + 16 + 8 * hi);
    short8 bv0 = *(const short8*)(vrow + k0 + 8 * hi);
    short8 bv1 = *(const short8*)(vrow + k0 + 16 + 8 * hi);
    __builtin_amdgcn_s_setprio(1);
    f32x16 pA = __builtin_amdgcn_mfma_f32_32x32x16_bf16(ak0, bqa0, z16, 0, 0, 0);
    f32x16 pB = __builtin_amdgcn_mfma_f32_32x32x16_bf16(ak0, bqb0, z16, 0, 0, 0);
    pA = __builtin_amdgcn_mfma_f32_32x32x16_bf16(ak1, bqa1, pA, 0, 0, 0);
    pB = __builtin_amdgcn_mfma_f32_32x32x16_bf16(ak1, bqb1, pB, 0, 0, 0);
    __builtin_amdgcn_s_setprio(0);
    union { unsigned u[4]; short8 s8; } fA0, fA1, fB0, fB1;
#pragma unroll
    for (int m = 0; m < 4; ++m)
      fA0.u[m] = cvt_pk_bf16(fexp2(pA[2 * m]), fexp2(pA[2 * m + 1]));
#pragma unroll
    for (int m = 0; m < 4; ++m)
      fA1.u[m] = cvt_pk_bf16(fexp2(pA[8 + 2 * m]), fexp2(pA[9 + 2 * m]));
#pragma unroll
    for (int m = 0; m < 4; ++m)
      fB0.u[m] = cvt_pk_bf16(fexp2(pB[2 * m]), fexp2(pB[2 * m + 1]));
#pragma unroll
    for (int m = 0; m < 4; ++m)
      fB1.u[m] = cvt_pk_bf16(fexp2(pB[8 + 2 * m]), fexp2(pB[9 + 2 * m]));
    __builtin_amdgcn_s_setprio(1);
    accA = __builtin_amdgcn_mfma_f32_32x32x16_bf16(fA0.s8, bv0, accA, 0, 0, 0);
    accB = __builtin_amdgcn_mfma_f32_32x32x16_bf16(fB0.s8, bv0, accB, 0, 0, 0);
    accA = __builtin_amdgcn_mfma_f32_32x32x16_bf16(fA1.s8, bv1, accA, 0, 0, 0);
    accB = __builtin_amdgcn_mfma_f32_32x32x16_bf16(fB1.s8, bv1, accB, 0, 0, 0);
    __builtin_amdgcn_s_setprio(0);
    ak0 = nak0;
    ak1 = nak1;
    k0 = kn;
  }
  short* part = parts + (size_t)ks * (S * DM);
  int col = h * 32 + lo;
#pragma unroll
  for (int r = 0; r < 16; ++r) {
    int qrel = (r & 3) + 8 * (r >> 2) + 4 * hi;
    part[(q0a + qrel) * 256 + col] = f2bf(accA[r]);
    part[(q0b + qrel) * 256 + col] = f2bf(accB[r]);
  }
}

// ---------- fused combine + LN2 + FFN GEMM: 256 blocks, 16 rows each.
// Recomputes LN1 from h0 (identical fp32 math), adds 8 bf16 parts -> xt (LDS),
// LN2 -> swizzled bf16 LDS A-tile, then GEMM + relu + residual -> hpad. ----------
__global__ __launch_bounds__(256) void k_ffn_fused(const float* __restrict__ h0,
                                                   const short* __restrict__ parts,
                                                   const float* __restrict__ lng,
                                                   const float* __restrict__ lnb,
                                                   const short* __restrict__ wb,
                                                   const float* __restrict__ bi,
                                                   short* __restrict__ hpad) {
  __shared__ short h2l[4096];       // LN2 output bf16, XOR-swizzled
  __shared__ float xtl[16][256];    // xt fp32 (residual)
  int m0 = blockIdx.x * 16;
  int tid = threadIdx.x;
  {
    int r = tid >> 4, cg = tid & 15;
    int row = m0 + r;
    float u[16];
    const float* hp = h0 + row * 256 + cg * 16;
#pragma unroll
    for (int i = 0; i < 16; i += 4) {
      float4 a = *(const float4*)(hp + i);
      u[i] = a.x; u[i + 1] = a.y; u[i + 2] = a.z; u[i + 3] = a.w;
    }
    float s1 = 0.f, s2 = 0.f;
#pragma unroll
    for (int i = 0; i < 16; ++i) { s1 += u[i]; s2 += u[i] * u[i]; }
    s1 += __shfl_xor(s1, 1); s2 += __shfl_xor(s2, 1);
    s1 += __shfl_xor(s1, 2); s2 += __shfl_xor(s2, 2);
    s1 += __shfl_xor(s1, 4); s2 += __shfl_xor(s2, 4);
    s1 += __shfl_xor(s1, 8); s2 += __shfl_xor(s2, 8);
    float m1 = s1 * (1.f / 256.f);
    float rstd1 = rsqrtf(s2 * (1.f / 256.f) - m1 * m1 + 1e-5f);
    float gv[16], bvv[16];
#pragma unroll
    for (int i = 0; i < 16; i += 4) {
      float4 a = *(const float4*)(lng + cg * 16 + i);
      float4 b = *(const float4*)(lnb + cg * 16 + i);
      gv[i] = a.x; gv[i + 1] = a.y; gv[i + 2] = a.z; gv[i + 3] = a.w;
      bvv[i] = b.x; bvv[i + 1] = b.y; bvv[i + 2] = b.z; bvv[i + 3] = b.w;
    }
    float xv[16];
#pragma unroll
    for (int i = 0; i < 16; ++i) xv[i] = (u[i] - m1) * rstd1 * gv[i] + bvv[i];
    const int SD4 = S * DM;
#pragma unroll
    for (int j = 0; j < 8; ++j) {
      const short* pp = parts + j * SD4 + row * 256 + cg * 16;
      short8 p0 = *(const short8*)(pp);
      short8 p1 = *(const short8*)(pp + 8);
#pragma unroll
      for (int i = 0; i < 8; ++i) { xv[i] += bf2f(p0[i]); xv[8 + i] += bf2f(p1[i]); }
    }
    s1 = 0.f; s2 = 0.f;
#pragma unroll
    for (int i = 0; i < 16; ++i) { s1 += xv[i]; s2 += xv[i] * xv[i]; }
    s1 += __shfl_xor(s1, 1); s2 += __shfl_xor(s2, 1);
    s1 += __shfl_xor(s1, 2); s2 += __shfl_xor(s2, 2);
    s1 += __shfl_xor(s1, 4); s2 += __shfl_xor(s2, 4);
    s1 += __shfl_xor(s1, 8); s2 += __shfl_xor(s2, 8);
    float m2 = s1 * (1.f / 256.f);
    float rstd2 = rsqrtf(s2 * (1.f / 256.f) - m2 * m2 + 1e-5f);
#pragma unroll
    for (int i = 0; i < 16; i += 4) {
      float4 a;
      a.x = xv[i]; a.y = xv[i + 1]; a.z = xv[i + 2]; a.w = xv[i + 3];
      *(float4*)(&xtl[r][cg * 16 + i]) = a;
    }
    union { unsigned uu[4]; short8 s8; } o0, o1;
#pragma unroll
    for (int i = 0; i < 8; i += 2) {
      float y0 = (xv[i] - m2) * rstd2 * gv[i] + bvv[i];
      float y1 = (xv[i + 1] - m2) * rstd2 * gv[i + 1] + bvv[i + 1];
      o0.uu[i >> 1] = cvt_pk_bf16(y0, y1);
      float y8 = (xv[8 + i] - m2) * rstd2 * gv[8 + i] + bvv[8 + i];
      float y9 = (xv[9 + i] - m2) * rstd2 * gv[9 + i] + bvv[9 + i];
      o1.uu[i >> 1] = cvt_pk_bf16(y8, y9);
    }
    char* base = (char*)h2l;
    *(short8*)(base + ((r * 512 + cg * 32) ^ ((r & 7) << 4))) = o0.s8;
    *(short8*)(base + ((r * 512 + cg * 32 + 16) ^ ((r & 7) << 4))) = o1.s8;
  }
  __syncthreads();
  // GEMM
  int w = tid >> 6, lane = tid & 63, g = lane >> 4, c = lane & 15;
  int nb = w * 64;
  f32x4 acc[4];
#pragma unroll
  for (int n = 0; n < 4; ++n) acc[n] = {0.f, 0.f, 0.f, 0.f};
  const char* abase = (const char*)h2l;
#pragma unroll 2
  for (int k0 = 0; k0 < 256; k0 += 32) {
    short8 af = *(const short8*)(abase + ((c * 512 + (k0 + 8 * g) * 2) ^ ((c & 7) << 4)));
#pragma unroll
    for (int n = 0; n < 4; ++n) {
      short8 bf = *(const short8*)(wb + (nb + 16 * n + c) * 256 + k0 + 8 * g);
      acc[n] = __builtin_amdgcn_mfma_f32_16x16x32_bf16(af, bf, acc[n], 0, 0, 0);
    }
  }
  int pr[4];
#pragma unroll
  for (int i = 0; i < 4; ++i) pr[i] = pad_idx(m0 + 4 * g + i) * 256;
#pragma unroll
  for (int n = 0; n < 4; ++n) {
    int o = nb + 16 * n + c;
    float bvv = bi[o];
#pragma unroll
    for (int i = 0; i < 4; ++i) {
      float v = acc[n][i] + bvv;
      v = v > 0.f ? v : 0.f;
      hpad[pr[i] + o] = f2bf(v + xtl[4 * g + i][o]);
    }
  }
}

// ---------- conv2 via MFMA, K-split x4, 32 m-rows/block (B-frag reuse x2) ----------
__global__ __launch_bounds__(256) void k_conv2m(const short* __restrict__ hpad,
                                                const short* __restrict__ wt,
                                                float* __restrict__ pbase) {
  __shared__ float red[3][32][65];
  int bid = blockIdx.x;  // 512 = mt2(128) x kh(4)
  int mt2 = bid >> 2, kh = bid & 3;
  int tid = threadIdx.x, w = tid >> 6, lane = tid & 63, g = lane >> 4, c = lane & 15;
  int d = mt2 >> 3, h = (mt2 & 7) * 2;
  f32x4 accA[4], accB[4];
#pragma unroll
  for (int n = 0; n < 4; ++n) { accA[n] = {0.f, 0.f, 0.f, 0.f}; accB[n] = {0.f, 0.f, 0.f, 0.f}; }
  int off0 = kh * 7;
  int offn = (kh == 3) ? 6 : 7;
  for (int off = off0 + w; off < off0 + offn; off += 4) {
    int kd = off / 9, rr = off - kd * 9, kkh = rr / 3, kw = rr - kkh * 3;
    int rowb = ((d + kd) * 18 + h + kkh) * 18 + kw + c;
    const short* arowA = hpad + rowb * 256;
    const short* arowB = hpad + (rowb + 18) * 256;
    const short* wrow = wt + off * 256;
#pragma unroll 2
    for (int kc = 0; kc < 8; ++kc) {
      short8 afA = *(const short8*)(arowA + kc * 32 + 8 * g);
      short8 afB = *(const short8*)(arowB + kc * 32 + 8 * g);
#pragma unroll
      for (int n = 0; n < 4; ++n) {
        short8 bf = *(const short8*)(wrow + (16 * n + c) * 6912 + kc * 32 + 8 * g);
        accA[n] = __builtin_amdgcn_mfma_f32_16x16x32_bf16(afA, bf, accA[n], 0, 0, 0);
        accB[n] = __builtin_amdgcn_mfma_f32_16x16x32_bf16(afB, bf, accB[n], 0, 0, 0);
      }
    }
  }
  if (w > 0) {
#pragma unroll
    for (int n = 0; n < 4; ++n)
#pragma unroll
      for (int i = 0; i < 4; ++i) {
        red[w - 1][n * 4 + i][lane] = accA[n][i];
        red[w - 1][16 + n * 4 + i][lane] = accB[n][i];
      }
  }
  __syncthreads();
  if (w == 0) {
    float* pbuf = pbase + (size_t)kh * (S * DM / 4);  // 64*4096 each
#pragma unroll
    for (int n = 0; n < 4; ++n) {
      int o = 16 * n + c;
      float4 stA, stB;
#pragma unroll
      for (int i = 0; i < 4; ++i) {
        float a = accA[n][i] + red[0][n * 4 + i][lane] + red[1][n * 4 + i][lane] + red[2][n * 4 + i][lane];
        float bb = accB[n][i] + red[0][16 + n * 4 + i][lane] + red[1][16 + n * 4 + i][lane] + red[2][16 + n * 4 + i][lane];
        ((float*)&stA)[i] = a;
        ((float*)&stB)[i] = bb;
      }
      *(float4*)(pbuf + o * 4096 + mt2 * 32 + 4 * g) = stA;
      *(float4*)(pbuf + o * 4096 + mt2 * 32 + 16 + 4 * g) = stB;
    }
  }
}

__global__ __launch_bounds__(256) void k_conv2fin(const float* __restrict__ pbase,
                                                  const float* __restrict__ bias,
                                                  float* __restrict__ out) {
  int idx4 = (blockIdx.x * 256 + threadIdx.x) * 4;  // 262144 total
  int o = idx4 >> 12;
  const int PS = S * DM / 4;  // 262144
  float4 a = *(const float4*)(pbase + idx4);
  float4 b = *(const float4*)(pbase + PS + idx4);
  float4 c = *(const float4*)(pbase + 2 * PS + idx4);
  float4 d = *(const float4*)(pbase + 3 * PS + idx4);
  float bv = bias[o];
  float4 r;
  r.x = a.x + b.x + c.x + d.x + bv;
  r.y = a.y + b.y + c.y + d.y + bv;
  r.z = a.z + b.z + c.z + d.z + bv;
  r.w = a.w + b.w + c.w + d.w + bv;
  *(float4*)(out + idx4) = r;
}

extern "C" void kernel_launch(void* const* d_in, const int* in_sizes, int n_in,
                              void* d_out, int out_size, void* d_ws, size_t ws_size,
                              hipStream_t stream) {
  const float* x   = (const float*)d_in[0];
  const float* c1w = (const float*)d_in[1];
  const float* c1b = (const float*)d_in[2];
  const float* lng = (const float*)d_in[3];
  const float* lnb = (const float*)d_in[4];
  const float* qw  = (const float*)d_in[5];
  const float* qbi = (const float*)d_in[6];
  const float* kw  = (const float*)d_in[7];
  const float* kbi = (const float*)d_in[8];
  const float* vw  = (const float*)d_in[9];
  const float* vbi = (const float*)d_in[10];
  const float* fw  = (const float*)d_in[11];
  const float* fbi = (const float*)d_in[12];
  const float* c2w = (const float*)d_in[13];
  const float* c2b = (const float*)d_in[14];
  float* out = (float*)d_out;
  float* ws = (float*)d_ws;

  const size_t SD = (size_t)S * DM;  // 1048576
  float* h0     = ws;                  // SD floats (live until ffn)
  short* partsb = (short*)(h0 + SD);   // 8*SD shorts (16MB)
  float* c2p    = (float*)partsb;      // alias: conv2 partials (parts dead by then)
  float* lpart  = (float*)(partsb + 8 * SD);  // 262144 floats
  short* qb     = (short*)(lpart + 262144);
  short* kb     = qb + SD;
  short* vt     = kb + SD;
  short* xpad   = vt + SD;             // 373248
  short* hpad   = xpad + 373248;       // 1492992
  short* w1t    = hpad + 1492992;      // 442368
  short* w2t    = w1t + 442368;        // 442368
  short* wqb    = w2t + 442368;        // 4 x 65536 contiguous
  short* wkb    = wqb + 65536;
  short* wvb    = wkb + 65536;
  short* wfb    = wvb + 65536;

  k_prep<<<3531, 256, 0, stream>>>(x, c1w, c2w, qw, kw, vw, fw,
                                   xpad, w1t, w2t, wqb, hpad);

  k_conv1m<<<256, 256, 0, stream>>>(xpad, w1t, c1b, h0);

  k_gemm_qkv<<<dim3(256, 3), 256, 0, stream>>>(h0, lng, lnb, wqb, wkb, wvb,
                                               qbi, kbi, vbi, qb, kb, vt);

  k_attn1<<<2048, 256, 0, stream>>>(qb, kb, lpart);
  k_scalevt<<<512, 256, 0, stream>>>(vt, lpart);
  k_attn2<<<1024, 256, 0, stream>>>(qb, kb, vt, partsb);

  k_ffn_fused<<<256, 256, 0, stream>>>(h0, partsb, lng, lnb, wfb, fbi, hpad);

  k_conv2m<<<512, 256, 0, stream>>>(hpad, w2t, c2p);
  k_conv2fin<<<256, 256, 0, stream>>>(c2p, c2b, out);
}